// Round 6
// baseline (613.539 us; speedup 1.0000x reference)
//
#include <hip/hip_runtime.h>

// GraphSAGE fused pipeline, bf16-MFMA v4: LDS-FREE, BARRIER-FREE GEMMs.
// Rationale (R5 post-mortem): __syncthreads forces vmcnt(0), draining all
// prefetch every iter. W (<=128KB) is L2/L1-resident and A has no cross-wave
// reuse beyond L1 -> skip LDS entirely. Each lane loads its MFMA fragment
// directly from global, 2-deep register pipeline, zero barriers -> compiler
// emits fine-grained vmcnt, loads stay in flight across iters.
// MFMA 16x16x32_bf16 layouts (verified R3-R5 pass):
//   A-frag: lane holds A[m=lane&15][k=(lane>>4)*8+j]   (fragment = 16B at
//           row*K + quad*8 -- directly loadable!)
//   B-frag: lane holds W[n=lane&15][k=(lane>>4)*8+j]   (C = A @ W^T)
//   C/D   : col=lane&15, row=(lane>>4)*4+reg

typedef __bf16 bf16_t;
typedef bf16_t bf16x8 __attribute__((ext_vector_type(8)));
typedef float  f32x4  __attribute__((ext_vector_type(4)));

__device__ inline bf16x8 cvt8(const float4 a, const float4 b) {
  bf16x8 t;
  t[0]=(bf16_t)a.x; t[1]=(bf16_t)a.y; t[2]=(bf16_t)a.z; t[3]=(bf16_t)a.w;
  t[4]=(bf16_t)b.x; t[5]=(bf16_t)b.y; t[6]=(bf16_t)b.z; t[7]=(bf16_t)b.w;
  return t;
}

template<typename AT> struct PreA {            // f32 source: cvt at use
  float4 lo, hi;
  __device__ void fetch(const AT* p) { lo = *(const float4*)p; hi = *(const float4*)(p + 4); }
  __device__ bf16x8 get() const { return cvt8(lo, hi); }
};
template<> struct PreA<bf16_t> {               // bf16 source: raw 16B
  bf16x8 v;
  __device__ void fetch(const bf16_t* p) { v = *(const bf16x8*)p; }
  __device__ bf16x8 get() const { return v; }
};

// ---- merged f32->bf16 conversion: 9 segments, dst contiguous in ws ----
struct CvtArgs { const float* src[9]; int start[9]; };  // start in elements

__global__ __launch_bounds__(256) void cvt_all(CvtArgs a, bf16_t* __restrict__ dst) {
  const int i = (blockIdx.x * 256 + threadIdx.x) * 8;
  int seg = 0;
#pragma unroll
  for (int s = 1; s < 9; ++s) if (i >= a.start[s]) seg = s;
  const float* src = a.src[seg] + (i - a.start[seg]);
  const float4 lo = *(const float4*)src;
  const float4 hi = *(const float4*)(src + 4);
  *(bf16x8*)(dst + i) = cvt8(lo, hi);
}

// ---- pooled GEMM: out[p][0:256] = max_{s<S} relu(A[p*S+s] @ W^T) * mask ----
// Block: 256 thr = 4 waves; wave wv -> n-tiles wv*4..wv*4+3; all waves cover
// all PM m-tiles (A re-reads served by L1). P parents x PR padded rows = 64.
template<int S, int PR, int P, int K, typename AT>
__global__ __launch_bounds__(256, 2) void pool_direct(
    const AT* __restrict__ A, const bf16_t* __restrict__ W,
    const float* __restrict__ mask, bf16_t* __restrict__ out)
{
  constexpr int PM  = (P * PR) / 16;           // 4 m-tiles
  constexpr int MTP = PR / 16;
  constexpr int T   = K / 32;
  const int tid  = threadIdx.x;
  const int lane = tid & 63, wv = tid >> 6, quad = lane >> 4, lrow = lane & 15;
  const long p0  = (long)blockIdx.x * P;

  const AT* aptr[PM];
#pragma unroll
  for (int pm = 0; pm < PM; ++pm) {
    const int mr = pm * 16 + lrow;
    const int pp = mr / PR, rr = mr % PR;
    const long grow = (p0 + pp) * (long)S + (rr < S ? rr : S - 1);  // clamp pads
    aptr[pm] = A + grow * (long)K + quad * 8;
  }
  const bf16_t* bptr[4];
#pragma unroll
  for (int nl = 0; nl < 4; ++nl) {
    const int n = (wv * 4 + nl) * 16 + lrow;
    bptr[nl] = W + (long)n * K + quad * 8;
  }

  f32x4 acc[PM][4];
#pragma unroll
  for (int pm = 0; pm < PM; ++pm)
#pragma unroll
    for (int nl = 0; nl < 4; ++nl) acc[pm][nl] = (f32x4){0.f, 0.f, 0.f, 0.f};

  PreA<AT> abuf[2][PM];
  bf16x8   bbuf[2][4];
#pragma unroll
  for (int pm = 0; pm < PM; ++pm) { abuf[0][pm].fetch(aptr[pm]); abuf[1][pm].fetch(aptr[pm] + 32); }
#pragma unroll
  for (int nl = 0; nl < 4; ++nl)  { bbuf[0][nl] = *(const bf16x8*)bptr[nl];
                                    bbuf[1][nl] = *(const bf16x8*)(bptr[nl] + 32); }

#pragma unroll
  for (int i = 0; i < T; ++i) {
    const int cur = i & 1;
    bf16x8 afr[PM], bfr[4];
#pragma unroll
    for (int pm = 0; pm < PM; ++pm) afr[pm] = abuf[cur][pm].get();
#pragma unroll
    for (int nl = 0; nl < 4; ++nl)  bfr[nl] = bbuf[cur][nl];
    if (i + 2 < T) {                            // refill: distance-2 pipeline
#pragma unroll
      for (int pm = 0; pm < PM; ++pm) abuf[cur][pm].fetch(aptr[pm] + (i + 2) * 32);
#pragma unroll
      for (int nl = 0; nl < 4; ++nl)  bbuf[cur][nl] = *(const bf16x8*)(bptr[nl] + (i + 2) * 32);
    }
#pragma unroll
    for (int pm = 0; pm < PM; ++pm)
#pragma unroll
      for (int nl = 0; nl < 4; ++nl)
        acc[pm][nl] = __builtin_amdgcn_mfma_f32_16x16x32_bf16(
            afr[pm], bfr[nl], acc[pm][nl], 0, 0, 0);
  }

  // epilogue: relu -> *mask -> max over S rows per parent (masks via direct
  // global loads, broadcast across the 16 lanes of a quad)
#pragma unroll
  for (int p = 0; p < P; ++p) {
    float mv[MTP][4];
#pragma unroll
    for (int mt = 0; mt < MTP; ++mt)
#pragma unroll
      for (int reg = 0; reg < 4; ++reg) {
        const int row = mt * 16 + quad * 4 + reg;
        mv[mt][reg] = (row < S) ? mask[(p0 + p) * S + row] : 0.f;
      }
#pragma unroll
    for (int nl = 0; nl < 4; ++nl) {
      float m = 0.f;
#pragma unroll
      for (int mt = 0; mt < MTP; ++mt) {
        const f32x4 v = acc[p * MTP + mt][nl];
#pragma unroll
        for (int reg = 0; reg < 4; ++reg)
          m = fmaxf(m, fmaxf(v[reg], 0.f) * mv[mt][reg]);
      }
      m = fmaxf(m, __shfl_xor(m, 16));
      m = fmaxf(m, __shfl_xor(m, 32));
      if (lane < 16)
        out[(p0 + p) * 256 + (wv * 4 + nl) * 16 + lrow] = (bf16_t)m;
    }
  }
}

// ---- plain GEMM: out[r][coff + 0:N] = A[r] @ W^T ; (A,W,coff) by blockIdx.y ----
template<int MTW, int NTW, int N, int K, typename OT>
__global__ __launch_bounds__(64 * (N / (16 * NTW))) void plain_direct(
    const bf16_t* __restrict__ A0, const bf16_t* __restrict__ W0, int c0,
    const bf16_t* __restrict__ A1, const bf16_t* __restrict__ W1, int c1,
    OT* __restrict__ out, int ldc)
{
  constexpr int T = K / 32;
  const bf16_t* __restrict__ A = blockIdx.y ? A1 : A0;
  const bf16_t* __restrict__ W = blockIdx.y ? W1 : W0;
  const int coff = blockIdx.y ? c1 : c0;

  const int tid  = threadIdx.x;
  const int lane = tid & 63, wv = tid >> 6, quad = lane >> 4, lrow = lane & 15;
  const long r0  = (long)blockIdx.x * (MTW * 16);

  const bf16_t* aptr[MTW];
#pragma unroll
  for (int mt = 0; mt < MTW; ++mt)
    aptr[mt] = A + (r0 + mt * 16 + lrow) * (long)K + quad * 8;
  const bf16_t* bptr[NTW];
#pragma unroll
  for (int nl = 0; nl < NTW; ++nl)
    bptr[nl] = W + (long)((wv * NTW + nl) * 16 + lrow) * K + quad * 8;

  f32x4 acc[MTW][NTW];
#pragma unroll
  for (int mt = 0; mt < MTW; ++mt)
#pragma unroll
    for (int nl = 0; nl < NTW; ++nl) acc[mt][nl] = (f32x4){0.f, 0.f, 0.f, 0.f};

  bf16x8 abuf[2][MTW], bbuf[2][NTW];
#pragma unroll
  for (int mt = 0; mt < MTW; ++mt) { abuf[0][mt] = *(const bf16x8*)aptr[mt];
                                     abuf[1][mt] = *(const bf16x8*)(aptr[mt] + 32); }
#pragma unroll
  for (int nl = 0; nl < NTW; ++nl) { bbuf[0][nl] = *(const bf16x8*)bptr[nl];
                                     bbuf[1][nl] = *(const bf16x8*)(bptr[nl] + 32); }

#pragma unroll
  for (int i = 0; i < T; ++i) {
    const int cur = i & 1;
    bf16x8 afr[MTW], bfr[NTW];
#pragma unroll
    for (int mt = 0; mt < MTW; ++mt) afr[mt] = abuf[cur][mt];
#pragma unroll
    for (int nl = 0; nl < NTW; ++nl) bfr[nl] = bbuf[cur][nl];
    if (i + 2 < T) {
#pragma unroll
      for (int mt = 0; mt < MTW; ++mt) abuf[cur][mt] = *(const bf16x8*)(aptr[mt] + (i + 2) * 32);
#pragma unroll
      for (int nl = 0; nl < NTW; ++nl) bbuf[cur][nl] = *(const bf16x8*)(bptr[nl] + (i + 2) * 32);
    }
#pragma unroll
    for (int mt = 0; mt < MTW; ++mt)
#pragma unroll
      for (int nl = 0; nl < NTW; ++nl)
        acc[mt][nl] = __builtin_amdgcn_mfma_f32_16x16x32_bf16(
            afr[mt], bfr[nl], acc[mt][nl], 0, 0, 0);
  }

#pragma unroll
  for (int mt = 0; mt < MTW; ++mt)
#pragma unroll
    for (int nl = 0; nl < NTW; ++nl) {
      const f32x4 v = acc[mt][nl];
      const int col = coff + (wv * NTW + nl) * 16 + lrow;
#pragma unroll
      for (int reg = 0; reg < 4; ++reg) {
        const long row = r0 + mt * 16 + quad * 4 + reg;
        out[row * (long)ldc + col] = (OT)v[reg];
      }
    }
}

extern "C" void kernel_launch(void* const* d_in, const int* in_sizes, int n_in,
                              void* d_out, int out_size, void* d_ws, size_t ws_size,
                              hipStream_t stream) {
  const float* h0f   = (const float*)d_in[0];
  const float* h1f   = (const float*)d_in[1];
  const float* h2    = (const float*)d_in[2];
  const float* mask0 = (const float*)d_in[3];
  const float* mask1 = (const float*)d_in[4];
  float* out = (float*)d_out;

  // bf16 conversions: 7 weights + h0 + h1, dst contiguous from ws base
  const int sz[9] = { 65536, 65536, 65536, 131072, 131072, 65536, 65536,
                      262144, 2621440 };                     // = 3,473,408 total
  CvtArgs ca;
  ca.src[0] = (const float*)d_in[5];  ca.src[1] = (const float*)d_in[6];
  ca.src[2] = (const float*)d_in[7];  ca.src[3] = (const float*)d_in[8];
  ca.src[4] = (const float*)d_in[9];  ca.src[5] = (const float*)d_in[10];
  ca.src[6] = (const float*)d_in[11]; ca.src[7] = h0f; ca.src[8] = h1f;
  bf16_t* p = (bf16_t*)d_ws;
  bf16_t* seg[9];
  { int off = 0;
    for (int i = 0; i < 9; ++i) { ca.start[i] = off; seg[i] = p + off; off += sz[i]; } }
  const bf16_t *Ws0 = seg[0], *Wn0 = seg[1], *Wp0 = seg[2], *Ws1 = seg[3],
               *Wn1 = seg[4], *Wp1 = seg[5], *Wout = seg[6],
               *h0b = seg[7], *h1b = seg[8];
  bf16_t* q = p + 3473408;
  bf16_t* pooled1  = q; q += 10240L * 256;
  bf16_t* states1  = q; q += 10240L * 512;
  bf16_t* pooled0  = q; q += 1024L * 256;
  bf16_t* states0  = q; q += 1024L * 512;
  bf16_t* pooled1b = q; q += 1024L * 256;
  bf16_t* states0b = q; q += 1024L * 512;

  const dim3 blk(256);

  // 0. all f32->bf16 conversions, one launch (3473408/8/256 = 1696 blocks)
  hipLaunchKernelGGL(cvt_all, dim3(1696), blk, 0, stream, ca, p);

  // 1. pooled1 = pool25(relu(h2 @ Wn0^T) * mask1)   [dominant, A stays f32]
  hipLaunchKernelGGL((pool_direct<25, 32, 2, 256, float>), dim3(5120), blk, 0, stream,
                     h2, Wn0, mask1, pooled1);
  // 2. pooled0 = pool10(relu(h1 @ Wn0^T) * mask0)
  hipLaunchKernelGGL((pool_direct<10, 16, 4, 256, bf16_t>), dim3(256), blk, 0, stream,
                     h1b, Wn0, mask0, pooled0);
  // 3+4. states1 = [h1 @ Ws0^T | pooled1 @ Wp0^T]
  hipLaunchKernelGGL((plain_direct<2, 4, 256, 256, bf16_t>), dim3(320, 2), blk, 0, stream,
                     h1b, Ws0, 0, pooled1, Wp0, 256, states1, 512);
  // 5+6. states0 = [h0 @ Ws0^T | pooled0 @ Wp0^T]
  hipLaunchKernelGGL((plain_direct<1, 4, 256, 256, bf16_t>), dim3(64, 2), blk, 0, stream,
                     h0b, Ws0, 0, pooled0, Wp0, 256, states0, 512);
  // 7. pooled1b = pool10(relu(states1 @ Wn1^T) * mask0), K=512
  hipLaunchKernelGGL((pool_direct<10, 16, 4, 512, bf16_t>), dim3(256), blk, 0, stream,
                     states1, Wn1, mask0, pooled1b);
  // 8. states0b[:, 0:256] = states0 @ Ws1^T, K=512
  hipLaunchKernelGGL((plain_direct<1, 4, 256, 512, bf16_t>), dim3(64, 1), blk, 0, stream,
                     states0, Ws1, 0, states0, Ws1, 0, states0b, 512);
  // 9. states0b[:, 256:512] = pooled1b @ Wp1^T, K=256
  hipLaunchKernelGGL((plain_direct<1, 4, 256, 256, bf16_t>), dim3(64, 1), blk, 0, stream,
                     pooled1b, Wp1, 256, pooled1b, Wp1, 256, states0b, 512);
  // 10. out = states0b @ Wout^T, K=512, N=128, f32 out (128-thread blocks)
  hipLaunchKernelGGL((plain_direct<1, 4, 128, 512, float>), dim3(64, 1), dim3(128), 0, stream,
                     states0b, Wout, 0, states0b, Wout, 0, out, 128);
}